// Round 1
// baseline (1996.792 us; speedup 1.0000x reference)
//
#include <hip/hip_runtime.h>
#include <cstdint>
#include <cstddef>

// Problem constants (fixed-shape problem).
#define N_ROWS 16384
#define D_IN   64
#define D_OUT  32
#define YSTRIDE 36              // floats per Yext row: 32 Y + gm1 + 1.0 + 2 pad (144 B, 16B-aligned)
#define KSPLITS 16              // total K-splits (4 grid groups x 4 waves/block)
#define KLEN   (N_ROWS / KSPLITS)   // 1024 columns per wave
#define NACC   34               // 32 nom + den + alpha

#define AS4 __attribute__((address_space(4)))   // constant addrspace -> s_load selection
using f4v = __attribute__((ext_vector_type(4))) float;   // align 16 == true alignment of our rows

__device__ __forceinline__ float artanh_c(float x) {
    // matches jnp.arctanh(clip(x, -1+1e-7, 1-1e-7))
    x = fminf(fmaxf(x, -1.0f + 1e-7f), 1.0f - 1e-7f);
    return 0.5f * logf((1.0f + x) / (1.0f - x));
}

// ---------------------------------------------------------------------------
// Kernel 1: per-row Mobius matvec + conformal-factor prep.
// Yext[j][0..31] = XW[j][:] * gamma_j ; [32] = gamma_j - 1 ; [33] = 1 ; [34..35] = 0
// ---------------------------------------------------------------------------
__global__ __launch_bounds__(256) void k1_rowprep(
        const float* __restrict__ X, const float* __restrict__ W,
        float* __restrict__ Yext) {
    const int row = blockIdx.x * 256 + threadIdx.x;
    const float* xr = X + (size_t)row * D_IN;

    float x[D_IN];
    #pragma unroll
    for (int k = 0; k < D_IN; k += 4) {
        f4v t = *(const f4v*)(xr + k);
        x[k] = t[0]; x[k+1] = t[1]; x[k+2] = t[2]; x[k+3] = t[3];
    }
    float sx2 = 0.0f;
    #pragma unroll
    for (int k = 0; k < D_IN; ++k) sx2 = fmaf(x[k], x[k], sx2);
    const float xn = fmaxf(sqrtf(sx2), 1e-15f);

    // mx = X_row @ W, W via scalar (uniform) loads
    const AS4 float* Wc = (const AS4 float*)(uintptr_t)W;
    float mx[D_OUT];
    #pragma unroll
    for (int d = 0; d < D_OUT; ++d) mx[d] = 0.0f;
    #pragma unroll 8
    for (int k = 0; k < D_IN; ++k) {
        const float xk = x[k];
        #pragma unroll
        for (int d = 0; d < D_OUT; ++d)
            mx[d] = fmaf(xk, Wc[k * D_OUT + d], mx[d]);
    }
    float sm2 = 0.0f;
    #pragma unroll
    for (int d = 0; d < D_OUT; ++d) sm2 = fmaf(mx[d], mx[d], sm2);
    const float mxn = fmaxf(sqrtf(sm2), 1e-15f);

    const float scale = tanhf(mxn / xn * artanh_c(xn)) / mxn;   // XW = mx * scale
    float x2 = 0.0f;
    float xw[D_OUT];
    #pragma unroll
    for (int d = 0; d < D_OUT; ++d) {
        xw[d] = mx[d] * scale;
        x2 = fmaf(xw[d], xw[d], x2);
    }
    const float gamma = 2.0f / fmaxf(1.0f - x2, 1e-15f);        // K = -1

    float* yr = Yext + (size_t)row * YSTRIDE;
    #pragma unroll
    for (int d = 0; d < D_OUT; ++d) yr[d] = xw[d] * gamma;
    yr[32] = gamma - 1.0f;
    yr[33] = 1.0f;
    yr[34] = 0.0f;
    yr[35] = 0.0f;
}

// ---------------------------------------------------------------------------
// Kernel 2: fused A @ [Y | gm1 | 1] with 34 accumulators/row.
// lane = row within 64-row tile; A per-lane row streaming (no LDS, no barriers);
// Y rows are wave-uniform -> SMEM s_loads, consumed as SGPR operand of v_fmac.
// partials layout: [ks][d][row]  (row-major inner => coalesced)
// ---------------------------------------------------------------------------
__device__ __forceinline__ void load_y9(f4v y[9], const AS4 char* yb, int j) {
    const AS4 f4v* p = (const AS4 f4v*)(yb + (size_t)j * (YSTRIDE * 4));
    #pragma unroll
    for (int g = 0; g < 9; ++g) y[g] = p[g];
}

__global__ __launch_bounds__(256, 4) void k2_spmm(
        const float* __restrict__ A, const float* __restrict__ Yext,
        float* __restrict__ partials) {
    const int tile = blockIdx.x & 255;                       // 256 row tiles
    const int kb   = blockIdx.x >> 8;                        // 0..3
    const int wave = __builtin_amdgcn_readfirstlane((int)(threadIdx.x >> 6)); // uniform!
    const int lane = threadIdx.x & 63;
    const int ks   = kb * 4 + wave;                          // 0..15
    const int row  = tile * 64 + lane;

    const float* Ar = A + (size_t)row * N_ROWS + (size_t)ks * KLEN;
    const AS4 char* Yb = (const AS4 char*)(uintptr_t)Yext
                       + (size_t)ks * KLEN * (YSTRIDE * 4);

    float acc[NACC];
    #pragma unroll
    for (int d = 0; d < NACC; ++d) acc[d] = 0.0f;

    // software pipeline: A 2 quads ahead, Y 1 column ahead
    f4v av0 = *(const f4v*)(Ar + 0);
    f4v av1 = *(const f4v*)(Ar + 4);
    f4v y[9];
    load_y9(y, Yb, 0);

    for (int j0 = 0; j0 < KLEN; j0 += 4) {
        const int ja = (j0 + 8 < KLEN) ? (j0 + 8) : (KLEN - 4);
        f4v av2 = *(const f4v*)(Ar + ja);
        #pragma unroll
        for (int q = 0; q < 4; ++q) {
            int jn = j0 + q + 1;
            jn = (jn < KLEN) ? jn : (KLEN - 1);
            f4v yn[9];
            load_y9(yn, Yb, jn);                 // prefetch next column's Y (SMEM)
            const float a = av0[q];
            #pragma unroll
            for (int g = 0; g < 8; ++g) {
                #pragma unroll
                for (int c = 0; c < 4; ++c)
                    acc[g * 4 + c] = fmaf(a, y[g][c], acc[g * 4 + c]);
            }
            acc[32] = fmaf(a, y[8][0], acc[32]); // den += a * (gamma_j - 1)
            acc[33] += a;                        // alpha += a
            #pragma unroll
            for (int g = 0; g < 9; ++g) y[g] = yn[g];   // SSA-renamed, no real moves
        }
        av0 = av1;
        av1 = av2;
    }

    float* pb = partials + (size_t)ks * NACC * N_ROWS + row;
    #pragma unroll
    for (int d = 0; d < NACC; ++d)
        pb[(size_t)d * N_ROWS] = acc[d];         // lane-consecutive => coalesced
}

// ---------------------------------------------------------------------------
// Kernel 3: reduce K-splits + midpoint epilogue + manifold relu.
// ---------------------------------------------------------------------------
__global__ __launch_bounds__(256) void k3_epilogue(
        const float* __restrict__ partials, float* __restrict__ out) {
    const int row = blockIdx.x * 256 + threadIdx.x;

    float nom[D_OUT];
    #pragma unroll
    for (int d = 0; d < D_OUT; ++d) nom[d] = 0.0f;
    float den = 0.0f, alpha = 0.0f;

    for (int ks = 0; ks < KSPLITS; ++ks) {
        const float* pb = partials + (size_t)ks * NACC * N_ROWS + row;
        #pragma unroll
        for (int d = 0; d < D_OUT; ++d) nom[d] += pb[(size_t)d * N_ROWS];
        den   += pb[(size_t)32 * N_ROWS];
        alpha += pb[(size_t)33 * N_ROWS];
    }

    // den = sign(den) * max(|den|, 1e-10); two_mean = nom / den
    const float sgn = (den >= 0.0f) ? 1.0f : -1.0f;
    den = sgn * fmaxf(fabsf(den), 1e-10f);
    float two[D_OUT];
    float tn2 = 0.0f;
    #pragma unroll
    for (int d = 0; d < D_OUT; ++d) {
        two[d] = nom[d] / den;
        tn2 = fmaf(two[d], two[d], tn2);
    }
    // a_mean = mobius_scalar_mul(0.5, two_mean)
    const float tn = fmaxf(sqrtf(tn2), 1e-15f);
    const float f1 = tanhf(0.5f * artanh_c(tn)) / tn;
    float am[D_OUT];
    float an2 = 0.0f;
    #pragma unroll
    for (int d = 0; d < D_OUT; ++d) {
        am[d] = two[d] * f1;
        an2 = fmaf(am[d], am[d], an2);
    }
    // mobius_scalar_mul(alpha, a_mean)
    const float an = fmaxf(sqrtf(an2), 1e-15f);
    const float f2 = tanhf(alpha * artanh_c(an)) / an;
    float r[D_OUT];
    float rn2 = 0.0f;
    #pragma unroll
    for (int d = 0; d < D_OUT; ++d) {
        r[d] = am[d] * f2;
        rn2 = fmaf(r[d], r[d], rn2);
    }
    // manifold relu: expmap0(relu(logmap0(x)))
    const float rn = fmaxf(sqrtf(rn2), 1e-15f);
    const float fu = artanh_c(rn) / rn;
    float u[D_OUT];
    float un2 = 0.0f;
    #pragma unroll
    for (int d = 0; d < D_OUT; ++d) {
        u[d] = fmaxf(r[d] * fu, 0.0f);
        un2 = fmaf(u[d], u[d], un2);
    }
    const float un = fmaxf(sqrtf(un2), 1e-15f);
    const float fo = tanhf(un) / un;

    float* orow = out + (size_t)row * D_OUT;
    #pragma unroll
    for (int d = 0; d < D_OUT; ++d) orow[d] = u[d] * fo;
}

// ---------------------------------------------------------------------------
// Launcher. ws usage: Yext 16384*36*4 = 2,359,296 B ; partials 16*34*16384*4 =
// 35,651,584 B ; total ~38.0 MB.
// ---------------------------------------------------------------------------
extern "C" void kernel_launch(void* const* d_in, const int* in_sizes, int n_in,
                              void* d_out, int out_size, void* d_ws, size_t ws_size,
                              hipStream_t stream) {
    const float* X = (const float*)d_in[0];   // (16384, 64)
    const float* A = (const float*)d_in[1];   // (16384, 16384)
    const float* W = (const float*)d_in[2];   // (64, 32)
    float* out = (float*)d_out;               // (16384, 32)

    float* Yext     = (float*)d_ws;
    float* partials = Yext + (size_t)N_ROWS * YSTRIDE;

    k1_rowprep<<<N_ROWS / 256, 256, 0, stream>>>(X, W, Yext);
    k2_spmm<<<256 * (KSPLITS / 4), 256, 0, stream>>>(A, Yext, partials);
    k3_epilogue<<<N_ROWS / 256, 256, 0, stream>>>(partials, out);
}